// Round 8
// baseline (136.911 us; speedup 1.0000x reference)
//
#include <hip/hip_runtime.h>

#define EPS_F 1e-8f
#define BLOCK 256

__device__ __forceinline__ float fast_rcp(float x) {
    return __builtin_amdgcn_rcpf(x);  // v_rcp_f32, ~1 ulp
}

__global__ void zero_out_kernel(float* out) { out[0] = 0.f; }

// Edge (a->b) contribution to 2*signed-Area(P ∩ [-W,W]x[-H,H]) via the
// boundary integral of h(y)=clamp(y,-H,H)+H over the edge clipped to the
// x-slab (vertical closure segments have dx=0 -> 0). Split at y=±H
// crossings; trapezoid per piece exact. Branch-free, NaN-free.
__device__ __forceinline__ float edge_contrib(float ax, float ay,
                                              float bx, float by,
                                              float W, float H) {
    float dx = bx - ax, dy = by - ay;
    float sdx = (fabsf(dx) < 1e-20f) ? 1e-20f : dx;
    float sdy = (fabsf(dy) < 1e-20f) ? 1e-20f : dy;
    float rdx = fast_rcp(sdx);
    float rdy = fast_rcp(sdy);

    float tA = (-W - ax) * rdx;
    float tB = ( W - ax) * rdx;
    float ta = fmaxf(fminf(tA, tB), 0.f);
    float tb = fminf(fmaxf(tA, tB), 1.f);
    tb = fmaxf(ta, tb);

    float u0 = (-H - ay) * rdy;
    float u1 = ( H - ay) * rdy;
    float tm0 = fminf(u0, u1), tm1 = fmaxf(u0, u1);
    float t1 = fminf(fmaxf(tm0, ta), tb);
    float t2 = fminf(fmaxf(tm1, ta), tb);

    float x0 = fmaf(ta, dx, ax), y0 = fmaf(ta, dy, ay);
    float x1 = fmaf(t1, dx, ax), y1 = fmaf(t1, dy, ay);
    float x2 = fmaf(t2, dx, ax), y2 = fmaf(t2, dy, ay);
    float x3 = fmaf(tb, dx, ax), y3 = fmaf(tb, dy, ay);
    float h0 = fminf(fmaxf(y0, -H), H) + H;
    float h1 = fminf(fmaxf(y1, -H), H) + H;
    float h2 = fminf(fmaxf(y2, -H), H) + H;
    float h3 = fminf(fmaxf(y3, -H), H) + H;

    return (x1 - x0) * (h0 + h1) + (x2 - x1) * (h1 + h2) + (x3 - x2) * (h2 + h3);
}

// EPT=1, 8 waves/SIMD (VGPR<=64): rely on TLP + wave refill, not per-wave ILP.
__global__ __launch_bounds__(BLOCK, 8) void iou3d_loss_kernel(
    const float* __restrict__ pred, const float* __restrict__ target,
    const float* __restrict__ weight, float* __restrict__ out,
    int N, float invN)
{
    int i = blockIdx.x * BLOCK + threadIdx.x;
    int j = (i < N) ? i : 0;                 // safe index; wgt=0 kills OOB
    long o = (long)j * 7;

    // hoisted independent loads (15 dwords; one drain)
    float a0 = pred[o],   a1 = pred[o+1],   a2 = pred[o+2],   a3 = pred[o+3];
    float a4 = pred[o+4], a5 = pred[o+5],   a6 = pred[o+6];
    float b0 = target[o],   b1 = target[o+1], b2 = target[o+2], b3 = target[o+3];
    float b4 = target[o+4], b5 = target[o+5], b6 = target[o+6];
    float wgt = (i < N) ? weight[j] : 0.f;

    float s1, c1, s2, c2;
    __sincosf(a6, &s1, &c1);
    __sincosf(b6, &s2, &c2);
    float cd = c1 * c2 + s1 * s2;            // cos(a2-a1)
    float sd = c1 * s2 - s1 * c2;            // sin(a2-a1)
    float dxc = b0 - a0, dyc = b1 - a1;
    float tx =  c1 * dxc + s1 * dyc;
    float ty = -s1 * dxc + c1 * dyc;
    float W = 0.5f * a3, H = 0.5f * a4;
    float w2 = 0.5f * b3, h2 = 0.5f * b4;

    // box2 corners in box1 frame (CCW)
    float cw = cd * w2, sw = sd * w2, ch = cd * h2, sh = sd * h2;
    float q0x =  cw - sh + tx, q0y =  sw + ch + ty;
    float q1x = -cw - sh + tx, q1y = -sw + ch + ty;
    float q2x = -cw + sh + tx, q2y = -sw - ch + ty;
    float q3x =  cw + sh + tx, q3y =  sw - ch + ty;

    float s  = edge_contrib(q0x, q0y, q1x, q1y, W, H)
             + edge_contrib(q1x, q1y, q2x, q2y, W, H)
             + edge_contrib(q2x, q2y, q3x, q3y, W, H)
             + edge_contrib(q3x, q3y, q0x, q0y, W, H);
    float area = 0.5f * fabsf(s);

    float zmax = fminf(a2 + 0.5f * a5, b2 + 0.5f * b5);
    float zmin = fmaxf(a2 - 0.5f * a5, b2 - 0.5f * b5);
    float inter3d = area * fmaxf(zmax - zmin, 0.f);
    float v1 = a3 * a4 * a5;
    float v2 = b3 * b4 * b5;
    float iou = inter3d * fast_rcp(v1 + v2 - inter3d + EPS_F);
    float val = (1.f - iou) * wgt;

    // ---- reduction: wave64 shuffle -> LDS -> one atomic per block ----
    #pragma unroll
    for (int off = 32; off > 0; off >>= 1) val += __shfl_down(val, off, 64);
    __shared__ float wsum[4];
    int lane = threadIdx.x & 63, wid = threadIdx.x >> 6;
    if (lane == 0) wsum[wid] = val;
    __syncthreads();
    if (threadIdx.x == 0) {
        float ssum = (wsum[0] + wsum[1] + wsum[2] + wsum[3]) * invN;
        atomicAdd(out, ssum);
    }
}

extern "C" void kernel_launch(void* const* d_in, const int* in_sizes, int n_in,
                              void* d_out, int out_size, void* d_ws, size_t ws_size,
                              hipStream_t stream) {
    const float* pred   = (const float*)d_in[0];
    const float* target = (const float*)d_in[1];
    const float* weight = (const float*)d_in[2];
    float* out = (float*)d_out;
    int N = in_sizes[2];  // weight element count

    zero_out_kernel<<<1, 1, 0, stream>>>(out);
    int grid = (N + BLOCK - 1) / BLOCK;
    iou3d_loss_kernel<<<grid, BLOCK, 0, stream>>>(pred, target, weight, out,
                                                  N, 1.f / (float)N);
}

// Round 9
// 100.263 us; speedup vs baseline: 1.3655x; 1.3655x over previous
//
#include <hip/hip_runtime.h>

#define EPS_F 1e-8f
#define BLOCK 256

typedef float vf4 __attribute__((ext_vector_type(4)));

__device__ __forceinline__ vf4 load4u(const float* p) {
    vf4 v;
    __builtin_memcpy(&v, p, 16);   // align-4 16B load -> global_load_dwordx4
    return v;
}

__device__ __forceinline__ float fast_rcp(float x) {
    return __builtin_amdgcn_rcpf(x);  // v_rcp_f32, ~1 ulp
}

__global__ void zero_out_kernel(float* out) { out[0] = 0.f; }

// Edge (a->b) contribution to 2*signed-Area(P ∩ [-W,W]x[-H,H]) via the
// boundary integral of h(y)=clamp(y,-H,H)+H over the edge clipped to the
// x-slab (vertical closure segments have dx=0 -> 0). Split at y=±H
// crossings; trapezoid per piece exact. Branch-free, NaN-free.
__device__ __forceinline__ float edge_contrib(float ax, float ay,
                                              float bx, float by,
                                              float W, float H) {
    float dx = bx - ax, dy = by - ay;
    float sdx = (fabsf(dx) < 1e-20f) ? 1e-20f : dx;
    float sdy = (fabsf(dy) < 1e-20f) ? 1e-20f : dy;
    float rdx = fast_rcp(sdx);
    float rdy = fast_rcp(sdy);

    float tA = (-W - ax) * rdx;
    float tB = ( W - ax) * rdx;
    float ta = fmaxf(fminf(tA, tB), 0.f);
    float tb = fminf(fmaxf(tA, tB), 1.f);
    tb = fmaxf(ta, tb);

    float u0 = (-H - ay) * rdy;
    float u1 = ( H - ay) * rdy;
    float tm0 = fminf(u0, u1), tm1 = fmaxf(u0, u1);
    float t1 = fminf(fmaxf(tm0, ta), tb);
    float t2 = fminf(fmaxf(tm1, ta), tb);

    float x0 = fmaf(ta, dx, ax), y0 = fmaf(ta, dy, ay);
    float x1 = fmaf(t1, dx, ax), y1 = fmaf(t1, dy, ay);
    float x2 = fmaf(t2, dx, ax), y2 = fmaf(t2, dy, ay);
    float x3 = fmaf(tb, dx, ax), y3 = fmaf(tb, dy, ay);
    float h0 = fminf(fmaxf(y0, -H), H) + H;
    float h1 = fminf(fmaxf(y1, -H), H) + H;
    float h2 = fminf(fmaxf(y2, -H), H) + H;
    float h3 = fminf(fmaxf(y3, -H), H) + H;

    return (x1 - x0) * (h0 + h1) + (x2 - x1) * (h1 + h2) + (x3 - x2) * (h2 + h3);
}

// Grid-slab loop with loop-carried prefetch (depth 1): next element's loads
// are in flight while the current element computes. Loop-carried registers
// force the compiler to keep the prefetch hoisted above the compute.
__global__ __launch_bounds__(BLOCK, 4) void iou3d_loss_kernel(
    const float* __restrict__ pred, const float* __restrict__ target,
    const float* __restrict__ weight, float* __restrict__ out,
    int N, float invN, int stride, int iters)
{
    int i = blockIdx.x * BLOCK + threadIdx.x;

    // ---- prologue: prefetch element 0 ----
    int j = (i < N) ? i : 0;
    long o = (long)j * 7;
    vf4 A0 = load4u(pred + o),  A1 = load4u(pred + o + 3);
    vf4 B0 = load4u(target + o), B1 = load4u(target + o + 3);
    float wg = (i < N) ? weight[j] : 0.f;

    float val = 0.f;
    #pragma unroll 1
    for (int it = 0; it < iters; ++it) {
        // ---- rotate pipeline: current <- prefetched ----
        vf4 a0 = A0, a1 = A1, b0 = B0, b1 = B1;
        float w = wg;

        // ---- issue next element's loads (independent of compute below) ----
        int inext = i + stride;
        if (it + 1 < iters) {                 // wave-uniform branch
            int jn = (inext < N) ? inext : 0;
            long on = (long)jn * 7;
            A0 = load4u(pred + on);  A1 = load4u(pred + on + 3);
            B0 = load4u(target + on); B1 = load4u(target + on + 3);
            wg = (inext < N) ? weight[jn] : 0.f;
        }
        i = inext;

        // ---- compute current element (hides the in-flight loads) ----
        // box: x=.x y=.y z=.z | w=.x h=.y l=.z yaw=.w
        float s1, c1, s2, c2;
        __sincosf(a1.w, &s1, &c1);
        __sincosf(b1.w, &s2, &c2);
        float cd = c1 * c2 + s1 * s2;          // cos(a2-a1)
        float sd = c1 * s2 - s1 * c2;          // sin(a2-a1)
        float dxc = b0.x - a0.x, dyc = b0.y - a0.y;
        float tx =  c1 * dxc + s1 * dyc;
        float ty = -s1 * dxc + c1 * dyc;
        float W = 0.5f * a1.x, H = 0.5f * a1.y;
        float w2 = 0.5f * b1.x, h2 = 0.5f * b1.y;

        float cw = cd * w2, sw = sd * w2, ch = cd * h2, sh = sd * h2;
        float q0x =  cw - sh + tx, q0y =  sw + ch + ty;
        float q1x = -cw - sh + tx, q1y = -sw + ch + ty;
        float q2x = -cw + sh + tx, q2y = -sw - ch + ty;
        float q3x =  cw + sh + tx, q3y =  sw - ch + ty;

        float s  = edge_contrib(q0x, q0y, q1x, q1y, W, H)
                 + edge_contrib(q1x, q1y, q2x, q2y, W, H)
                 + edge_contrib(q2x, q2y, q3x, q3y, W, H)
                 + edge_contrib(q3x, q3y, q0x, q0y, W, H);
        float area = 0.5f * fabsf(s);

        float zmax = fminf(a0.z + 0.5f * a1.z, b0.z + 0.5f * b1.z);
        float zmin = fmaxf(a0.z - 0.5f * a1.z, b0.z - 0.5f * b1.z);
        float inter3d = area * fmaxf(zmax - zmin, 0.f);
        float v1 = a1.x * a1.y * a1.z;
        float v2 = b1.x * b1.y * b1.z;
        float iou = inter3d * fast_rcp(v1 + v2 - inter3d + EPS_F);
        val += (1.f - iou) * w;
    }

    // ---- reduction: wave64 shuffle -> LDS -> one atomic per block ----
    #pragma unroll
    for (int off = 32; off > 0; off >>= 1) val += __shfl_down(val, off, 64);
    __shared__ float wsum[4];
    int lane = threadIdx.x & 63, wid = threadIdx.x >> 6;
    if (lane == 0) wsum[wid] = val;
    __syncthreads();
    if (threadIdx.x == 0) {
        float ssum = (wsum[0] + wsum[1] + wsum[2] + wsum[3]) * invN;
        atomicAdd(out, ssum);
    }
}

extern "C" void kernel_launch(void* const* d_in, const int* in_sizes, int n_in,
                              void* d_out, int out_size, void* d_ws, size_t ws_size,
                              hipStream_t stream) {
    const float* pred   = (const float*)d_in[0];
    const float* target = (const float*)d_in[1];
    const float* weight = (const float*)d_in[2];
    float* out = (float*)d_out;
    int N = in_sizes[2];  // weight element count

    zero_out_kernel<<<1, 1, 0, stream>>>(out);
    int nblocks = (N + BLOCK - 1) / BLOCK;
    int grid = (nblocks < 1024) ? nblocks : 1024;   // 4 blocks/CU, persistent
    int stride = grid * BLOCK;
    int iters = (N + stride - 1) / stride;          // 4 for N = 1M
    iou3d_loss_kernel<<<grid, BLOCK, 0, stream>>>(pred, target, weight, out,
                                                  N, 1.f / (float)N, stride, iters);
}